// Round 1
// 244.454 us; speedup vs baseline: 1.0086x; 1.0086x over previous
//
#include <hip/hip_runtime.h>

// MultiHeadedAttention B=2,S=2048,D=1024,H=16,Dh=64 — f32 in/out.
// Round 8 (softmax VALU diet in attn_mfma):
//   - exp2 direct: softmax scale folded as log2e/32 into Q epilogue, so the
//     attn inner loop calls v_exp_f32 (2^x) with no v_mul.
//   - mask as additive float bias (0 / -1e9), precomputed in cvt_all plane 7,
//     stored in the dead upper half of d_out; replaces cmp+cndmask with v_add.
//   - P pack via v_cvt_pk_bf16_f32 inline asm (2 dwords -> ds_write_b64),
//     replacing 16 manual 4-op f2bf conversions per iteration.
// MFMA frag layouts + XOR-slot swizzle hardware-verified (rounds 3-6).

typedef unsigned short ushort_t;
typedef __attribute__((ext_vector_type(8))) short short8;
typedef __attribute__((ext_vector_type(4))) float floatx4;

#define BATCH 2
#define SEQ   2048
#define DF    1024
#define NH    16
#define DH    64
#define MROWS 4096

__device__ __forceinline__ float bf2f(ushort_t u) {
    return __uint_as_float(((unsigned int)u) << 16);
}
__device__ __forceinline__ ushort_t f2bf(float f) {
    unsigned int u = __float_as_uint(f);
    u += 0x7FFFu + ((u >> 16) & 1u);   // RNE
    return (ushort_t)(u >> 16);
}

__device__ __forceinline__ float exp2_fast(float x) {
#if defined(__has_builtin)
#if __has_builtin(__builtin_amdgcn_exp2f)
    return __builtin_amdgcn_exp2f(x);
#else
    float r; asm("v_exp_f32 %0, %1" : "=v"(r) : "v"(x)); return r;
#endif
#else
    float r; asm("v_exp_f32 %0, %1" : "=v"(r) : "v"(x)); return r;
#endif
}

// ---------------------------------------------------------------------------
// Fused f32->bf16 conversion of 7 tensors + int-mask -> float-bias plane.
// ---------------------------------------------------------------------------
struct CvtArgs {
    const float* src[7];
    ushort_t*    dst[7];
    int          n[7];
    const int*   msrc;   // int mask  [B*S]
    float*       mdst;   // float bias [B*S]: mask? 0 : -1e9
};

__global__ __launch_bounds__(256) void cvt_all(CvtArgs a)
{
    const int y = blockIdx.y;
    if (y == 7) {
        int i = (blockIdx.x * 256 + threadIdx.x) * 4;
        if (i >= BATCH * SEQ) return;
        int4 m = *(const int4*)(a.msrc + i);
        float4 o;
        o.x = m.x ? 0.f : -1e9f;
        o.y = m.y ? 0.f : -1e9f;
        o.z = m.z ? 0.f : -1e9f;
        o.w = m.w ? 0.f : -1e9f;
        *(float4*)(a.mdst + i) = o;
        return;
    }
    const int n = a.n[y];
    int i = (blockIdx.x * 256 + threadIdx.x) * 4;
    if (i >= n) return;
    const float* in = a.src[y];
    ushort_t* out = a.dst[y];
    float4 v = *(const float4*)(in + i);
    ushort4 o;
    o.x = f2bf(v.x); o.y = f2bf(v.y); o.z = f2bf(v.z); o.w = f2bf(v.w);
    *(ushort4*)(out + i) = o;
}

// ---------------------------------------------------------------------------
// Fused QKV projections, all-bf16 operands. Grid (24,32): n0 = bx*128.
//   n0 <1024: Qf (A=Qb, bq, epilogue scale log2e/32 — folds softmax scale AND
//             the exp->exp2 conversion)
//   <2048:    Kf (A=Kb, bk)
//   else:     Vt DIRECT (A=Vb, bv) — transposed write [(b*16+h)*64+dh][s],
//             thread's 4 acc regs per (mt,nt) are 4 consecutive s -> ushort4.
// 128x128 tile, BK=64, global_load_lds staging, XOR-slot swizzle (verified).
// ---------------------------------------------------------------------------
__global__ __launch_bounds__(256) void gemm_qkv(
    const ushort_t* __restrict__ Qb, const ushort_t* __restrict__ Kb,
    const ushort_t* __restrict__ Vb, const ushort_t* __restrict__ Wcat,
    const float* __restrict__ bq, const float* __restrict__ bk,
    const float* __restrict__ bv,
    ushort_t* __restrict__ Qf, ushort_t* __restrict__ Kf,
    ushort_t* __restrict__ Vt)
{
    __shared__ ushort_t As[128 * 64];  // 16 KB, [row][slot], slot = k8 ^ (row&7)
    __shared__ ushort_t Bs[128 * 64];  // 16 KB

    const int t = threadIdx.x;
    const int lane = t & 63, w = t >> 6;
    const int x = lane & 15, y = lane >> 4;
    const int wm = (w >> 1) * 64, wn = (w & 1) * 64;
    const int m0 = blockIdx.y << 7, n0 = blockIdx.x << 7;

    const ushort_t* Ab; const float* bp;
    if (n0 < 1024)      { Ab = Qb; bp = bq; }
    else if (n0 < 2048) { Ab = Kb; bp = bk; }
    else                { Ab = Vb; bp = bv; }
    const int ncol0 = n0 & 1023;

    floatx4 acc[4][4] = {};

    for (int kt = 0; kt < 16; ++kt) {
        const int k0 = kt * 64;

        #pragma unroll
        for (int j = 0; j < 4; ++j) {   // A stage
            int i   = (w << 2) + j;
            int c   = (i << 6) + lane;
            int row = c >> 3;
            int s   = c & 7;
            int k8  = s ^ (row & 7);
            const ushort_t* g = Ab + (size_t)(m0 + row) * DF + k0 + (k8 << 3);
            __builtin_amdgcn_global_load_lds(
                (const __attribute__((address_space(1))) unsigned int*)g,
                (__attribute__((address_space(3))) unsigned int*)(As + (i << 9)),
                16, 0, 0);
        }
        #pragma unroll
        for (int j = 0; j < 4; ++j) {   // B stage
            int i   = (w << 2) + j;
            int c   = (i << 6) + lane;
            int row = c >> 3;
            int s   = c & 7;
            int k8  = s ^ (row & 7);
            const ushort_t* g = Wcat + (size_t)(n0 + row) * DF + k0 + (k8 << 3);
            __builtin_amdgcn_global_load_lds(
                (const __attribute__((address_space(1))) unsigned int*)g,
                (__attribute__((address_space(3))) unsigned int*)(Bs + (i << 9)),
                16, 0, 0);
        }
        __syncthreads();

        #pragma unroll
        for (int kh = 0; kh < 2; ++kh) {
            const int slot = ((kh << 2) + y) ^ (x & 7);
            short8 af[4], bfr[4];
            #pragma unroll
            for (int mt = 0; mt < 4; ++mt)
                af[mt] = *(const short8*)(As + (wm + (mt << 4) + x) * 64 + slot * 8);
            #pragma unroll
            for (int nt = 0; nt < 4; ++nt)
                bfr[nt] = *(const short8*)(Bs + (wn + (nt << 4) + x) * 64 + slot * 8);
            #pragma unroll
            for (int mt = 0; mt < 4; ++mt)
                #pragma unroll
                for (int nt = 0; nt < 4; ++nt)
                    acc[mt][nt] = __builtin_amdgcn_mfma_f32_16x16x32_bf16(
                        af[mt], bfr[nt], acc[mt][nt], 0, 0, 0);
        }
        __syncthreads();
    }

    float bvv[4];
    #pragma unroll
    for (int nt = 0; nt < 4; ++nt) bvv[nt] = bp[ncol0 + wn + (nt << 4) + x];

    if (n0 < 2048) {
        // Qf/Kf: natural layout, scale log2e/32 for Q (softmax scale + exp2 fold)
        ushort_t* outp = (n0 < 1024) ? Qf : Kf;
        const float osc = (n0 < 1024) ? 0.0450842200f : 1.0f;  // log2(e)/32
        #pragma unroll
        for (int mt = 0; mt < 4; ++mt) {
            #pragma unroll
            for (int r = 0; r < 4; ++r) {
                const size_t grow = (size_t)(m0 + wm + (mt << 4) + (y << 2) + r) * DF;
                #pragma unroll
                for (int nt = 0; nt < 4; ++nt)
                    outp[grow + ncol0 + wn + (nt << 4) + x] =
                        f2bf((acc[mt][nt][r] + bvv[nt]) * osc);
            }
        }
    } else {
        // V: direct transposed write to Vt[(b*16+h)*64+dh][s]
        #pragma unroll
        for (int mt = 0; mt < 4; ++mt) {
            int m   = m0 + wm + (mt << 4) + (y << 2);  // +r are consecutive s
            int bb2 = m >> 11;
            int s0  = m & 2047;
            #pragma unroll
            for (int nt = 0; nt < 4; ++nt) {
                int col = ncol0 + wn + (nt << 4) + x;  // h*64+dh
                ushort4 pk;
                pk.x = f2bf(acc[mt][nt][0] + bvv[nt]);
                pk.y = f2bf(acc[mt][nt][1] + bvv[nt]);
                pk.z = f2bf(acc[mt][nt][2] + bvv[nt]);
                pk.w = f2bf(acc[mt][nt][3] + bvv[nt]);
                *(ushort4*)(Vt + ((size_t)(bb2 << 10) + col) * 2048 + s0) = pk;
            }
        }
    }
}

// ---------------------------------------------------------------------------
// Out-projection: C[4096,1024] = Xr @ Wo^T + bo, f32 out.
// Tile 128(M) x 64(N), grid (16,32) = 512 blocks = 2/CU. Wave-tile 64x32.
// ---------------------------------------------------------------------------
__global__ __launch_bounds__(256) void gemm_out(
    const ushort_t* __restrict__ Xr, const ushort_t* __restrict__ Wb,
    const float* __restrict__ bias, float* __restrict__ C)
{
    __shared__ ushort_t As[128 * 64];  // 16 KB
    __shared__ ushort_t Bs[64 * 64];   // 8 KB

    const int t = threadIdx.x;
    const int lane = t & 63, w = t >> 6;
    const int x = lane & 15, y = lane >> 4;
    const int wm = (w >> 1) * 64, wn = (w & 1) * 32;
    const int m0 = blockIdx.y << 7, n0 = blockIdx.x << 6;

    floatx4 acc[4][2] = {};

    for (int kt = 0; kt < 16; ++kt) {
        const int k0 = kt * 64;

        #pragma unroll
        for (int j = 0; j < 4; ++j) {   // A stage: 16 KB
            int i   = (w << 2) + j;
            int c   = (i << 6) + lane;
            int row = c >> 3;
            int s   = c & 7;
            int k8  = s ^ (row & 7);
            const ushort_t* g = Xr + (size_t)(m0 + row) * DF + k0 + (k8 << 3);
            __builtin_amdgcn_global_load_lds(
                (const __attribute__((address_space(1))) unsigned int*)g,
                (__attribute__((address_space(3))) unsigned int*)(As + (i << 9)),
                16, 0, 0);
        }
        #pragma unroll
        for (int j = 0; j < 2; ++j) {   // B stage: 8 KB
            int i   = (w << 1) + j;
            int c   = (i << 6) + lane;
            int row = c >> 3;
            int s   = c & 7;
            int k8  = s ^ (row & 7);
            const ushort_t* g = Wb + (size_t)(n0 + row) * DF + k0 + (k8 << 3);
            __builtin_amdgcn_global_load_lds(
                (const __attribute__((address_space(1))) unsigned int*)g,
                (__attribute__((address_space(3))) unsigned int*)(Bs + (i << 9)),
                16, 0, 0);
        }
        __syncthreads();

        #pragma unroll
        for (int kh = 0; kh < 2; ++kh) {
            const int slot = ((kh << 2) + y) ^ (x & 7);
            short8 af[4], bfr[2];
            #pragma unroll
            for (int mt = 0; mt < 4; ++mt)
                af[mt] = *(const short8*)(As + (wm + (mt << 4) + x) * 64 + slot * 8);
            #pragma unroll
            for (int nt = 0; nt < 2; ++nt)
                bfr[nt] = *(const short8*)(Bs + (wn + (nt << 4) + x) * 64 + slot * 8);
            #pragma unroll
            for (int mt = 0; mt < 4; ++mt)
                #pragma unroll
                for (int nt = 0; nt < 2; ++nt)
                    acc[mt][nt] = __builtin_amdgcn_mfma_f32_16x16x32_bf16(
                        af[mt], bfr[nt], acc[mt][nt], 0, 0, 0);
        }
        __syncthreads();
    }

    float bvv[2];
    #pragma unroll
    for (int nt = 0; nt < 2; ++nt) bvv[nt] = bias[n0 + wn + (nt << 4) + x];

    #pragma unroll
    for (int mt = 0; mt < 4; ++mt) {
        #pragma unroll
        for (int r = 0; r < 4; ++r) {
            const size_t grow = (size_t)(m0 + wm + (mt << 4) + (y << 2) + r) * DF;
            #pragma unroll
            for (int nt = 0; nt < 2; ++nt)
                C[grow + n0 + wn + (nt << 4) + x] = acc[mt][nt][r] + bvv[nt];
        }
    }
}

// ---------------------------------------------------------------------------
// Attention, full MFMA, S^T variant.
// QK^T swapped: sacc[mt] = mfma(kfrag, qfrag) -> D[row=key][col=q]; thread
// (x,y) owns keys mt*16+y*4..+3 for q=wm+x. Softmax: additive float bias
// (preconverted mask), raw v_exp_f32 (scale folded into Q), P packed via
// v_cvt_pk_bf16_f32 -> ds_write_b64. P region wave-local -> no mid barrier.
// 2 barriers/tile. LDS 24 KB.
// ---------------------------------------------------------------------------
__global__ __launch_bounds__(256) void attn_mfma(
    const ushort_t* __restrict__ Qf, const ushort_t* __restrict__ Kf,
    const ushort_t* __restrict__ Vt, const float* __restrict__ maskb,
    ushort_t* __restrict__ Xr)
{
    __shared__ ushort_t Qs[64 * 64];  // 8 KB; becomes Ps after qfrag extraction
    __shared__ ushort_t Ks[64 * 64];  // 8 KB
    __shared__ ushort_t Vs[64 * 64];  // 8 KB ([dh][key] tile of Vt)
    ushort_t* Ps = Qs;

    const int t = threadIdx.x;
    const int lane = t & 63, w = t >> 6;
    const int x = lane & 15, y = lane >> 4;
    const int wm = w << 4;
    const int b = blockIdx.z, h = blockIdx.y;
    const int q0 = blockIdx.x << 6;
    const size_t qkbase = ((size_t)b * SEQ) * DF + (size_t)h * DH;
    const size_t vbase  = ((size_t)(b * NH + h) * DH) * SEQ;
    const int mbase = b * SEQ;

    #pragma unroll
    for (int j = 0; j < 2; ++j) {
        int i   = (w << 1) + j;
        int c   = (i << 6) + lane;
        int row = c >> 3;
        int s   = c & 7;
        int k8  = s ^ (row & 7);
        const ushort_t* g = Qf + qkbase + (size_t)(q0 + row) * DF + (k8 << 3);
        __builtin_amdgcn_global_load_lds(
            (const __attribute__((address_space(1))) unsigned int*)g,
            (__attribute__((address_space(3))) unsigned int*)(Qs + (i << 9)),
            16, 0, 0);
    }
    __syncthreads();

    short8 qfrag[2];
    #pragma unroll
    for (int kh = 0; kh < 2; ++kh) {
        int slot = ((kh << 2) + y) ^ (x & 7);
        qfrag[kh] = *(const short8*)(Qs + (wm + x) * 64 + slot * 8);
    }
    // qfrag reads drain at the first in-loop barrier, before any Ps write.

    floatx4 oacc[4] = {};
    float dsum = 0.f;

    for (int kt = 0; kt < 32; ++kt) {
        const int k0 = kt << 6;

        #pragma unroll
        for (int j = 0; j < 4; ++j) {
            int i   = (w << 2) + j;
            int c   = (i << 6) + lane;
            int row = (c >> 3) & 63;
            int s   = c & 7;
            int k8  = s ^ (row & 7);
            if (i < 8) {
                const ushort_t* g = Kf + qkbase + (size_t)(k0 + row) * DF + (k8 << 3);
                __builtin_amdgcn_global_load_lds(
                    (const __attribute__((address_space(1))) unsigned int*)g,
                    (__attribute__((address_space(3))) unsigned int*)(Ks + (i << 9)),
                    16, 0, 0);
            } else {
                const ushort_t* g = Vt + vbase + (size_t)row * SEQ + k0 + (k8 << 3);
                __builtin_amdgcn_global_load_lds(
                    (const __attribute__((address_space(1))) unsigned int*)g,
                    (__attribute__((address_space(3))) unsigned int*)(Vs + ((i - 8) << 9)),
                    16, 0, 0);
            }
        }
        // mask-bias prefetch: thread needs keys mt*16 + y*4 .. +3
        float4 mb[4];
        #pragma unroll
        for (int mt = 0; mt < 4; ++mt)
            mb[mt] = *(const float4*)(maskb + mbase + k0 + (mt << 4) + (y << 2));

        __syncthreads();   // staging visible; prev-iter PV/QK reads drained

        // ---- S^T = K·Q^T: D[row=key][col=q], wave strip 64 keys x 16 q ----
        floatx4 sacc[4] = {};
        #pragma unroll
        for (int kh = 0; kh < 2; ++kh) {
            const int slot = ((kh << 2) + y) ^ (x & 7);
            #pragma unroll
            for (int mt = 0; mt < 4; ++mt) {
                short8 kf = *(const short8*)(Ks + ((mt << 4) + x) * 64 + slot * 8);
                sacc[mt] = __builtin_amdgcn_mfma_f32_16x16x32_bf16(
                    kf, qfrag[kh], sacc[mt], 0, 0, 0);
            }
        }

        // ---- softmax: bias-add + exp2 + packed P write (wave-local rows) ----
        #pragma unroll
        for (int mt = 0; mt < 4; ++mt) {
            float p0 = exp2_fast(sacc[mt][0] + mb[mt].x);
            float p1 = exp2_fast(sacc[mt][1] + mb[mt].y);
            float p2 = exp2_fast(sacc[mt][2] + mb[mt].z);
            float p3 = exp2_fast(sacc[mt][3] + mb[mt].w);
            dsum += (p0 + p1) + (p2 + p3);
            unsigned int w0, w1;
            asm("v_cvt_pk_bf16_f32 %0, %1, %2" : "=v"(w0) : "v"(p0), "v"(p1));
            asm("v_cvt_pk_bf16_f32 %0, %1, %2" : "=v"(w1) : "v"(p2), "v"(p3));
            uint2 pk; pk.x = w0; pk.y = w1;
            int slot2 = ((mt << 1) + (y >> 1)) ^ (x & 7);
            *(uint2*)(Ps + ((wm + x) << 6) + (slot2 << 3) + ((y & 1) << 2)) = pk;
        }

        // ---- PV: O strip 16q x 64dh (reads own wave's P rows) ----
        #pragma unroll
        for (int kh = 0; kh < 2; ++kh) {
            const int slot = ((kh << 2) + y) ^ (x & 7);
            short8 pf = *(const short8*)(Ps + (wm + x) * 64 + slot * 8);
            #pragma unroll
            for (int nt = 0; nt < 4; ++nt) {
                short8 vf = *(const short8*)(Vs + ((nt << 4) + x) * 64 + slot * 8);
                oacc[nt] = __builtin_amdgcn_mfma_f32_16x16x32_bf16(
                    pf, vf, oacc[nt], 0, 0, 0);
            }
        }
        __syncthreads();   // all reads drained before next staging
    }

    // dsum: thread holds partial for q=wm+x (keys y*4+r per tile);
    // reduce across the 4 y-lanes sharing x, then broadcast per output row.
    dsum += __shfl_xor(dsum, 16, 64);
    dsum += __shfl_xor(dsum, 32, 64);
    float rdv[4];
    #pragma unroll
    for (int r = 0; r < 4; ++r)
        rdv[r] = 1.0f / __shfl(dsum, (y << 2) + r, 64);

    #pragma unroll
    for (int r = 0; r < 4; ++r) {
        int q = q0 + wm + (y << 2) + r;
        #pragma unroll
        for (int nt = 0; nt < 4; ++nt)
            Xr[qkbase + (size_t)q * DF + (nt << 4) + x] = f2bf(oacc[nt][r] * rdv[r]);
    }
}

// ---------------------------------------------------------------------------
extern "C" void kernel_launch(void* const* d_in, const int* in_sizes, int n_in,
                              void* d_out, int out_size, void* d_ws, size_t ws_size,
                              hipStream_t stream)
{
    const float* Q    = (const float*)d_in[0];
    const float* K    = (const float*)d_in[1];
    const float* V    = (const float*)d_in[2];
    const int*   mask = (const int*)d_in[3];
    const float* Wq   = (const float*)d_in[4];
    const float* bq   = (const float*)d_in[5];
    const float* Wk   = (const float*)d_in[6];
    const float* bk   = (const float*)d_in[7];
    const float* Wv   = (const float*)d_in[8];
    const float* bv   = (const float*)d_in[9];
    const float* Wo   = (const float*)d_in[10];
    const float* bo   = (const float*)d_in[11];
    float* out = (float*)d_out;

    // ws (48 MB): Wcat 8 + Qf 8 + Kf 8 + Vt 8 + Xr 8 + Qb 8.
    // Aliases: Kb = Xr (dead before attn writes), Vb = d_out (first 8 MB,
    // dead before gemm_out writes), maskb = d_out second half (16 KB; attn
    // reads it before gemm_out overwrites d_out — stream-ordered).
    ushort_t* Wqb = (ushort_t*)d_ws;
    ushort_t* Wkb = Wqb + (1 << 20);
    ushort_t* Wvb = Wkb + (1 << 20);
    ushort_t* Wob = Wvb + (1 << 20);
    ushort_t* Qf  = Wob + (1 << 20);
    ushort_t* Kf  = Qf + (size_t)MROWS * DF;
    ushort_t* Vt  = Kf + (size_t)MROWS * DF;
    ushort_t* Xr  = Vt + (size_t)MROWS * DF;
    ushort_t* Qb  = Xr + (size_t)MROWS * DF;
    ushort_t* Kb  = Xr;
    ushort_t* Vb  = (ushort_t*)d_out;
    float*    maskb = (float*)((ushort_t*)d_out + (size_t)(1 << 22));  // +8 MB

    const int nin = MROWS * DF;  // 4M
    const int nw  = DF * DF;     // 1M

    CvtArgs ca;
    ca.src[0] = Q;  ca.dst[0] = Qb;  ca.n[0] = nin;
    ca.src[1] = K;  ca.dst[1] = Kb;  ca.n[1] = nin;
    ca.src[2] = V;  ca.dst[2] = Vb;  ca.n[2] = nin;
    ca.src[3] = Wq; ca.dst[3] = Wqb; ca.n[3] = nw;
    ca.src[4] = Wk; ca.dst[4] = Wkb; ca.n[4] = nw;
    ca.src[5] = Wv; ca.dst[5] = Wvb; ca.n[5] = nw;
    ca.src[6] = Wo; ca.dst[6] = Wob; ca.n[6] = nw;
    ca.msrc = mask;
    ca.mdst = maskb;

    dim3 blk(256);
    cvt_all<<<dim3(nin / 1024, 8), blk, 0, stream>>>(ca);

    gemm_qkv<<<dim3(24, 32), blk, 0, stream>>>(Qb, Kb, Vb, Wqb, bq, bk, bv,
                                               Qf, Kf, Vt);

    attn_mfma<<<dim3(SEQ / 64, NH, BATCH), blk, 0, stream>>>(Qf, Kf, Vt, maskb, Xr);

    gemm_out<<<dim3(16, 32), blk, 0, stream>>>(Xr, Wob, bo, out);
}

// Round 2
// 238.879 us; speedup vs baseline: 1.0322x; 1.0233x over previous
//
#include <hip/hip_runtime.h>

// MultiHeadedAttention B=2,S=2048,D=1024,H=16,Dh=64 — f32 in/out.
// Round 9 (attn latency hiding):
//   - K/V LDS double-buffered (24 -> 40 KB, still 4 blocks/CU): stage of
//     tile kt+1 issued at top of iteration kt, compute on buf[cur], ONE
//     __syncthreads per iteration (was 2). The barrier's vmcnt(0) drain now
//     lands after a full compute body instead of immediately after issue,
//     hiding the global->LDS latency; barrier count halves.
//   - mask-bias loads issued BEFORE the stage loads so the softmax waits at
//     vmcnt(4) (mask only) instead of vmcnt(0) (vmcnt retires in issue order).
// Round 8: exp2-direct softmax (scale log2e/32 folded into Q), additive mask
// bias plane, v_cvt_pk_bf16_f32 P-pack.
// MFMA frag layouts + XOR-slot swizzle hardware-verified (rounds 3-6).

typedef unsigned short ushort_t;
typedef __attribute__((ext_vector_type(8))) short short8;
typedef __attribute__((ext_vector_type(4))) float floatx4;

#define BATCH 2
#define SEQ   2048
#define DF    1024
#define NH    16
#define DH    64
#define MROWS 4096

__device__ __forceinline__ float bf2f(ushort_t u) {
    return __uint_as_float(((unsigned int)u) << 16);
}
__device__ __forceinline__ ushort_t f2bf(float f) {
    unsigned int u = __float_as_uint(f);
    u += 0x7FFFu + ((u >> 16) & 1u);   // RNE
    return (ushort_t)(u >> 16);
}

__device__ __forceinline__ float exp2_fast(float x) {
#if defined(__has_builtin)
#if __has_builtin(__builtin_amdgcn_exp2f)
    return __builtin_amdgcn_exp2f(x);
#else
    float r; asm("v_exp_f32 %0, %1" : "=v"(r) : "v"(x)); return r;
#endif
#else
    float r; asm("v_exp_f32 %0, %1" : "=v"(r) : "v"(x)); return r;
#endif
}

// ---------------------------------------------------------------------------
// Fused f32->bf16 conversion of 7 tensors + int-mask -> float-bias plane.
// ---------------------------------------------------------------------------
struct CvtArgs {
    const float* src[7];
    ushort_t*    dst[7];
    int          n[7];
    const int*   msrc;   // int mask  [B*S]
    float*       mdst;   // float bias [B*S]: mask? 0 : -1e9
};

__global__ __launch_bounds__(256) void cvt_all(CvtArgs a)
{
    const int y = blockIdx.y;
    if (y == 7) {
        int i = (blockIdx.x * 256 + threadIdx.x) * 4;
        if (i >= BATCH * SEQ) return;
        int4 m = *(const int4*)(a.msrc + i);
        float4 o;
        o.x = m.x ? 0.f : -1e9f;
        o.y = m.y ? 0.f : -1e9f;
        o.z = m.z ? 0.f : -1e9f;
        o.w = m.w ? 0.f : -1e9f;
        *(float4*)(a.mdst + i) = o;
        return;
    }
    const int n = a.n[y];
    int i = (blockIdx.x * 256 + threadIdx.x) * 4;
    if (i >= n) return;
    const float* in = a.src[y];
    ushort_t* out = a.dst[y];
    float4 v = *(const float4*)(in + i);
    ushort4 o;
    o.x = f2bf(v.x); o.y = f2bf(v.y); o.z = f2bf(v.z); o.w = f2bf(v.w);
    *(ushort4*)(out + i) = o;
}

// ---------------------------------------------------------------------------
// Fused QKV projections, all-bf16 operands. Grid (24,32): n0 = bx*128.
//   n0 <1024: Qf (A=Qb, bq, epilogue scale log2e/32 — folds softmax scale AND
//             the exp->exp2 conversion)
//   <2048:    Kf (A=Kb, bk)
//   else:     Vt DIRECT (A=Vb, bv) — transposed write [(b*16+h)*64+dh][s],
//             thread's 4 acc regs per (mt,nt) are 4 consecutive s -> ushort4.
// 128x128 tile, BK=64, global_load_lds staging, XOR-slot swizzle (verified).
// ---------------------------------------------------------------------------
__global__ __launch_bounds__(256) void gemm_qkv(
    const ushort_t* __restrict__ Qb, const ushort_t* __restrict__ Kb,
    const ushort_t* __restrict__ Vb, const ushort_t* __restrict__ Wcat,
    const float* __restrict__ bq, const float* __restrict__ bk,
    const float* __restrict__ bv,
    ushort_t* __restrict__ Qf, ushort_t* __restrict__ Kf,
    ushort_t* __restrict__ Vt)
{
    __shared__ ushort_t As[128 * 64];  // 16 KB, [row][slot], slot = k8 ^ (row&7)
    __shared__ ushort_t Bs[128 * 64];  // 16 KB

    const int t = threadIdx.x;
    const int lane = t & 63, w = t >> 6;
    const int x = lane & 15, y = lane >> 4;
    const int wm = (w >> 1) * 64, wn = (w & 1) * 64;
    const int m0 = blockIdx.y << 7, n0 = blockIdx.x << 7;

    const ushort_t* Ab; const float* bp;
    if (n0 < 1024)      { Ab = Qb; bp = bq; }
    else if (n0 < 2048) { Ab = Kb; bp = bk; }
    else                { Ab = Vb; bp = bv; }
    const int ncol0 = n0 & 1023;

    floatx4 acc[4][4] = {};

    for (int kt = 0; kt < 16; ++kt) {
        const int k0 = kt * 64;

        #pragma unroll
        for (int j = 0; j < 4; ++j) {   // A stage
            int i   = (w << 2) + j;
            int c   = (i << 6) + lane;
            int row = c >> 3;
            int s   = c & 7;
            int k8  = s ^ (row & 7);
            const ushort_t* g = Ab + (size_t)(m0 + row) * DF + k0 + (k8 << 3);
            __builtin_amdgcn_global_load_lds(
                (const __attribute__((address_space(1))) unsigned int*)g,
                (__attribute__((address_space(3))) unsigned int*)(As + (i << 9)),
                16, 0, 0);
        }
        #pragma unroll
        for (int j = 0; j < 4; ++j) {   // B stage
            int i   = (w << 2) + j;
            int c   = (i << 6) + lane;
            int row = c >> 3;
            int s   = c & 7;
            int k8  = s ^ (row & 7);
            const ushort_t* g = Wcat + (size_t)(n0 + row) * DF + k0 + (k8 << 3);
            __builtin_amdgcn_global_load_lds(
                (const __attribute__((address_space(1))) unsigned int*)g,
                (__attribute__((address_space(3))) unsigned int*)(Bs + (i << 9)),
                16, 0, 0);
        }
        __syncthreads();

        #pragma unroll
        for (int kh = 0; kh < 2; ++kh) {
            const int slot = ((kh << 2) + y) ^ (x & 7);
            short8 af[4], bfr[4];
            #pragma unroll
            for (int mt = 0; mt < 4; ++mt)
                af[mt] = *(const short8*)(As + (wm + (mt << 4) + x) * 64 + slot * 8);
            #pragma unroll
            for (int nt = 0; nt < 4; ++nt)
                bfr[nt] = *(const short8*)(Bs + (wn + (nt << 4) + x) * 64 + slot * 8);
            #pragma unroll
            for (int mt = 0; mt < 4; ++mt)
                #pragma unroll
                for (int nt = 0; nt < 4; ++nt)
                    acc[mt][nt] = __builtin_amdgcn_mfma_f32_16x16x32_bf16(
                        af[mt], bfr[nt], acc[mt][nt], 0, 0, 0);
        }
        __syncthreads();
    }

    float bvv[4];
    #pragma unroll
    for (int nt = 0; nt < 4; ++nt) bvv[nt] = bp[ncol0 + wn + (nt << 4) + x];

    if (n0 < 2048) {
        // Qf/Kf: natural layout, scale log2e/32 for Q (softmax scale + exp2 fold)
        ushort_t* outp = (n0 < 1024) ? Qf : Kf;
        const float osc = (n0 < 1024) ? 0.0450842200f : 1.0f;  // log2(e)/32
        #pragma unroll
        for (int mt = 0; mt < 4; ++mt) {
            #pragma unroll
            for (int r = 0; r < 4; ++r) {
                const size_t grow = (size_t)(m0 + wm + (mt << 4) + (y << 2) + r) * DF;
                #pragma unroll
                for (int nt = 0; nt < 4; ++nt)
                    outp[grow + ncol0 + wn + (nt << 4) + x] =
                        f2bf((acc[mt][nt][r] + bvv[nt]) * osc);
            }
        }
    } else {
        // V: direct transposed write to Vt[(b*16+h)*64+dh][s]
        #pragma unroll
        for (int mt = 0; mt < 4; ++mt) {
            int m   = m0 + wm + (mt << 4) + (y << 2);  // +r are consecutive s
            int bb2 = m >> 11;
            int s0  = m & 2047;
            #pragma unroll
            for (int nt = 0; nt < 4; ++nt) {
                int col = ncol0 + wn + (nt << 4) + x;  // h*64+dh
                ushort4 pk;
                pk.x = f2bf(acc[mt][nt][0] + bvv[nt]);
                pk.y = f2bf(acc[mt][nt][1] + bvv[nt]);
                pk.z = f2bf(acc[mt][nt][2] + bvv[nt]);
                pk.w = f2bf(acc[mt][nt][3] + bvv[nt]);
                *(ushort4*)(Vt + ((size_t)(bb2 << 10) + col) * 2048 + s0) = pk;
            }
        }
    }
}

// ---------------------------------------------------------------------------
// Out-projection: C[4096,1024] = Xr @ Wo^T + bo, f32 out.
// Tile 128(M) x 64(N), grid (16,32) = 512 blocks = 2/CU. Wave-tile 64x32.
// ---------------------------------------------------------------------------
__global__ __launch_bounds__(256) void gemm_out(
    const ushort_t* __restrict__ Xr, const ushort_t* __restrict__ Wb,
    const float* __restrict__ bias, float* __restrict__ C)
{
    __shared__ ushort_t As[128 * 64];  // 16 KB
    __shared__ ushort_t Bs[64 * 64];   // 8 KB

    const int t = threadIdx.x;
    const int lane = t & 63, w = t >> 6;
    const int x = lane & 15, y = lane >> 4;
    const int wm = (w >> 1) * 64, wn = (w & 1) * 32;
    const int m0 = blockIdx.y << 7, n0 = blockIdx.x << 6;

    floatx4 acc[4][2] = {};

    for (int kt = 0; kt < 16; ++kt) {
        const int k0 = kt * 64;

        #pragma unroll
        for (int j = 0; j < 4; ++j) {   // A stage: 16 KB
            int i   = (w << 2) + j;
            int c   = (i << 6) + lane;
            int row = c >> 3;
            int s   = c & 7;
            int k8  = s ^ (row & 7);
            const ushort_t* g = Xr + (size_t)(m0 + row) * DF + k0 + (k8 << 3);
            __builtin_amdgcn_global_load_lds(
                (const __attribute__((address_space(1))) unsigned int*)g,
                (__attribute__((address_space(3))) unsigned int*)(As + (i << 9)),
                16, 0, 0);
        }
        #pragma unroll
        for (int j = 0; j < 2; ++j) {   // B stage: 8 KB
            int i   = (w << 1) + j;
            int c   = (i << 6) + lane;
            int row = c >> 3;
            int s   = c & 7;
            int k8  = s ^ (row & 7);
            const ushort_t* g = Wb + (size_t)(n0 + row) * DF + k0 + (k8 << 3);
            __builtin_amdgcn_global_load_lds(
                (const __attribute__((address_space(1))) unsigned int*)g,
                (__attribute__((address_space(3))) unsigned int*)(Bs + (i << 9)),
                16, 0, 0);
        }
        __syncthreads();

        #pragma unroll
        for (int kh = 0; kh < 2; ++kh) {
            const int slot = ((kh << 2) + y) ^ (x & 7);
            short8 af[4], bfr[2];
            #pragma unroll
            for (int mt = 0; mt < 4; ++mt)
                af[mt] = *(const short8*)(As + (wm + (mt << 4) + x) * 64 + slot * 8);
            #pragma unroll
            for (int nt = 0; nt < 2; ++nt)
                bfr[nt] = *(const short8*)(Bs + (wn + (nt << 4) + x) * 64 + slot * 8);
            #pragma unroll
            for (int mt = 0; mt < 4; ++mt)
                #pragma unroll
                for (int nt = 0; nt < 2; ++nt)
                    acc[mt][nt] = __builtin_amdgcn_mfma_f32_16x16x32_bf16(
                        af[mt], bfr[nt], acc[mt][nt], 0, 0, 0);
        }
        __syncthreads();
    }

    float bvv[2];
    #pragma unroll
    for (int nt = 0; nt < 2; ++nt) bvv[nt] = bias[n0 + wn + (nt << 4) + x];

    #pragma unroll
    for (int mt = 0; mt < 4; ++mt) {
        #pragma unroll
        for (int r = 0; r < 4; ++r) {
            const size_t grow = (size_t)(m0 + wm + (mt << 4) + (y << 2) + r) * DF;
            #pragma unroll
            for (int nt = 0; nt < 2; ++nt)
                C[grow + n0 + wn + (nt << 4) + x] = acc[mt][nt][r] + bvv[nt];
        }
    }
}

// ---------------------------------------------------------------------------
// Attention, full MFMA, S^T variant, double-buffered K/V staging.
// QK^T swapped: sacc[mt] = mfma(kfrag, qfrag) -> D[row=key][col=q]; thread
// (x,y) owns keys mt*16+y*4..+3 for q=wm+x. Softmax: additive float bias
// (preconverted mask), raw v_exp_f32 (scale folded into Q), P packed via
// v_cvt_pk_bf16_f32 -> ds_write_b64. P region wave-local -> no mid barrier.
//
// Pipeline: stage(kt+1 -> buf^1) issued at top of iter kt; compute tile kt
// from buf; ONE __syncthreads at iteration end. Safety: the barrier's
// vmcnt(0)+lgkmcnt(0) drain guarantees (a) tile kt+1 LDS writes complete
// before any wave reads them in iter kt+1, (b) all ds_reads of buf^1 (iter
// kt-1 compute) completed before iter kt's stage overwrites it. Mask loads
// issued BEFORE stage loads: vmcnt retires in order, so softmax waits at
// vmcnt(4) leaving the 4 stage loads in flight. LDS 40 KB (4 blocks/CU,
// same as grid supplies).
// ---------------------------------------------------------------------------
__global__ __launch_bounds__(256) void attn_mfma(
    const ushort_t* __restrict__ Qf, const ushort_t* __restrict__ Kf,
    const ushort_t* __restrict__ Vt, const float* __restrict__ maskb,
    ushort_t* __restrict__ Xr)
{
    __shared__ ushort_t Qs[64 * 64];      // 8 KB; becomes Ps after qfrag extract
    __shared__ ushort_t Ks[2][64 * 64];   // 16 KB double-buffered
    __shared__ ushort_t Vs[2][64 * 64];   // 16 KB double-buffered
    ushort_t* Ps = Qs;

    const int t = threadIdx.x;
    const int lane = t & 63, w = t >> 6;
    const int x = lane & 15, y = lane >> 4;
    const int wm = w << 4;
    const int b = blockIdx.z, h = blockIdx.y;
    const int q0 = blockIdx.x << 6;
    const size_t qkbase = ((size_t)b * SEQ) * DF + (size_t)h * DH;
    const size_t vbase  = ((size_t)(b * NH + h) * DH) * SEQ;
    const int mbase = b * SEQ;

    // Staging geometry (per wave: 4 of the 16 tile-rows-of-8):
    const int i_s  = (w << 2);            // first i for K/V stage
    const int c0   = lane;                // column part reused every iter

    // ---- prologue: Q stage + K/V tile 0 into buf 0 ----
    #pragma unroll
    for (int j = 0; j < 2; ++j) {
        int i   = (w << 1) + j;
        int c   = (i << 6) + lane;
        int row = c >> 3;
        int s   = c & 7;
        int k8  = s ^ (row & 7);
        const ushort_t* g = Qf + qkbase + (size_t)(q0 + row) * DF + (k8 << 3);
        __builtin_amdgcn_global_load_lds(
            (const __attribute__((address_space(1))) unsigned int*)g,
            (__attribute__((address_space(3))) unsigned int*)(Qs + (i << 9)),
            16, 0, 0);
    }
    #pragma unroll
    for (int j = 0; j < 4; ++j) {
        int i   = i_s + j;
        int c   = (i << 6) + c0;
        int row = (c >> 3) & 63;
        int s   = c & 7;
        int k8  = s ^ (row & 7);
        if (i < 8) {
            const ushort_t* g = Kf + qkbase + (size_t)row * DF + (k8 << 3);
            __builtin_amdgcn_global_load_lds(
                (const __attribute__((address_space(1))) unsigned int*)g,
                (__attribute__((address_space(3))) unsigned int*)(Ks[0] + (i << 9)),
                16, 0, 0);
        } else {
            const ushort_t* g = Vt + vbase + (size_t)row * SEQ + (k8 << 3);
            __builtin_amdgcn_global_load_lds(
                (const __attribute__((address_space(1))) unsigned int*)g,
                (__attribute__((address_space(3))) unsigned int*)(Vs[0] + ((i - 8) << 9)),
                16, 0, 0);
        }
    }
    __syncthreads();

    short8 qfrag[2];
    #pragma unroll
    for (int kh = 0; kh < 2; ++kh) {
        int slot = ((kh << 2) + y) ^ (x & 7);
        qfrag[kh] = *(const short8*)(Qs + (wm + x) * 64 + slot * 8);
    }
    // qfrag ds_reads complete before the first QK^T MFMA (compiler lgkmcnt
    // wait), which precedes the first Ps write in program order; same-wave
    // DS ops complete in order -> no barrier needed before Ps reuse.

    floatx4 oacc[4] = {};
    float dsum = 0.f;

    for (int kt = 0; kt < 32; ++kt) {
        const int cur = kt & 1;
        const int k0 = kt << 6;

        // ---- mask-bias loads for THIS tile (issued first: vmcnt order) ----
        float4 mb[4];
        #pragma unroll
        for (int mt = 0; mt < 4; ++mt)
            mb[mt] = *(const float4*)(maskb + mbase + k0 + (mt << 4) + (y << 2));

        // ---- stage NEXT tile into the other buffer ----
        if (kt < 31) {
            const int k0n = (kt + 1) << 6;
            ushort_t* Kd = Ks[cur ^ 1];
            ushort_t* Vd = Vs[cur ^ 1];
            #pragma unroll
            for (int j = 0; j < 4; ++j) {
                int i   = i_s + j;
                int c   = (i << 6) + c0;
                int row = (c >> 3) & 63;
                int s   = c & 7;
                int k8  = s ^ (row & 7);
                if (i < 8) {
                    const ushort_t* g = Kf + qkbase + (size_t)(k0n + row) * DF + (k8 << 3);
                    __builtin_amdgcn_global_load_lds(
                        (const __attribute__((address_space(1))) unsigned int*)g,
                        (__attribute__((address_space(3))) unsigned int*)(Kd + (i << 9)),
                        16, 0, 0);
                } else {
                    const ushort_t* g = Vt + vbase + (size_t)row * SEQ + k0n + (k8 << 3);
                    __builtin_amdgcn_global_load_lds(
                        (const __attribute__((address_space(1))) unsigned int*)g,
                        (__attribute__((address_space(3))) unsigned int*)(Vd + ((i - 8) << 9)),
                        16, 0, 0);
                }
            }
        }

        // ---- S^T = K·Q^T on buf[cur]: D[row=key][col=q] ----
        const ushort_t* Kc = Ks[cur];
        const ushort_t* Vc = Vs[cur];
        floatx4 sacc[4] = {};
        #pragma unroll
        for (int kh = 0; kh < 2; ++kh) {
            const int slot = ((kh << 2) + y) ^ (x & 7);
            #pragma unroll
            for (int mt = 0; mt < 4; ++mt) {
                short8 kf = *(const short8*)(Kc + ((mt << 4) + x) * 64 + slot * 8);
                sacc[mt] = __builtin_amdgcn_mfma_f32_16x16x32_bf16(
                    kf, qfrag[kh], sacc[mt], 0, 0, 0);
            }
        }

        // ---- softmax: bias-add + exp2 + packed P write (wave-local rows) ----
        #pragma unroll
        for (int mt = 0; mt < 4; ++mt) {
            float p0 = exp2_fast(sacc[mt][0] + mb[mt].x);
            float p1 = exp2_fast(sacc[mt][1] + mb[mt].y);
            float p2 = exp2_fast(sacc[mt][2] + mb[mt].z);
            float p3 = exp2_fast(sacc[mt][3] + mb[mt].w);
            dsum += (p0 + p1) + (p2 + p3);
            unsigned int w0, w1;
            asm("v_cvt_pk_bf16_f32 %0, %1, %2" : "=v"(w0) : "v"(p0), "v"(p1));
            asm("v_cvt_pk_bf16_f32 %0, %1, %2" : "=v"(w1) : "v"(p2), "v"(p3));
            uint2 pk; pk.x = w0; pk.y = w1;
            int slot2 = ((mt << 1) + (y >> 1)) ^ (x & 7);
            *(uint2*)(Ps + ((wm + x) << 6) + (slot2 << 3) + ((y & 1) << 2)) = pk;
        }

        // ---- PV: O strip 16q x 64dh (reads own wave's P rows) ----
        #pragma unroll
        for (int kh = 0; kh < 2; ++kh) {
            const int slot = ((kh << 2) + y) ^ (x & 7);
            short8 pf = *(const short8*)(Ps + (wm + x) * 64 + slot * 8);
            #pragma unroll
            for (int nt = 0; nt < 4; ++nt) {
                short8 vf = *(const short8*)(Vc + ((nt << 4) + x) * 64 + slot * 8);
                oacc[nt] = __builtin_amdgcn_mfma_f32_16x16x32_bf16(
                    pf, vf, oacc[nt], 0, 0, 0);
            }
        }

        __syncthreads();   // tile kt+1 staged & visible; buf[cur] reads drained
    }

    // dsum: thread holds partial for q=wm+x (keys y*4+r per tile);
    // reduce across the 4 y-lanes sharing x, then broadcast per output row.
    dsum += __shfl_xor(dsum, 16, 64);
    dsum += __shfl_xor(dsum, 32, 64);
    float rdv[4];
    #pragma unroll
    for (int r = 0; r < 4; ++r)
        rdv[r] = 1.0f / __shfl(dsum, (y << 2) + r, 64);

    #pragma unroll
    for (int r = 0; r < 4; ++r) {
        int q = q0 + wm + (y << 2) + r;
        #pragma unroll
        for (int nt = 0; nt < 4; ++nt)
            Xr[qkbase + (size_t)q * DF + (nt << 4) + x] = f2bf(oacc[nt][r] * rdv[r]);
    }
}

// ---------------------------------------------------------------------------
extern "C" void kernel_launch(void* const* d_in, const int* in_sizes, int n_in,
                              void* d_out, int out_size, void* d_ws, size_t ws_size,
                              hipStream_t stream)
{
    const float* Q    = (const float*)d_in[0];
    const float* K    = (const float*)d_in[1];
    const float* V    = (const float*)d_in[2];
    const int*   mask = (const int*)d_in[3];
    const float* Wq   = (const float*)d_in[4];
    const float* bq   = (const float*)d_in[5];
    const float* Wk   = (const float*)d_in[6];
    const float* bk   = (const float*)d_in[7];
    const float* Wv   = (const float*)d_in[8];
    const float* bv   = (const float*)d_in[9];
    const float* Wo   = (const float*)d_in[10];
    const float* bo   = (const float*)d_in[11];
    float* out = (float*)d_out;

    // ws (48 MB): Wcat 8 + Qf 8 + Kf 8 + Vt 8 + Xr 8 + Qb 8.
    // Aliases: Kb = Xr (dead before attn writes), Vb = d_out (first 8 MB,
    // dead before gemm_out writes), maskb = d_out second half (16 KB; attn
    // reads it before gemm_out overwrites d_out — stream-ordered).
    ushort_t* Wqb = (ushort_t*)d_ws;
    ushort_t* Wkb = Wqb + (1 << 20);
    ushort_t* Wvb = Wkb + (1 << 20);
    ushort_t* Wob = Wvb + (1 << 20);
    ushort_t* Qf  = Wob + (1 << 20);
    ushort_t* Kf  = Qf + (size_t)MROWS * DF;
    ushort_t* Vt  = Kf + (size_t)MROWS * DF;
    ushort_t* Xr  = Vt + (size_t)MROWS * DF;
    ushort_t* Qb  = Xr + (size_t)MROWS * DF;
    ushort_t* Kb  = Xr;
    ushort_t* Vb  = (ushort_t*)d_out;
    float*    maskb = (float*)((ushort_t*)d_out + (size_t)(1 << 22));  // +8 MB

    const int nin = MROWS * DF;  // 4M
    const int nw  = DF * DF;     // 1M

    CvtArgs ca;
    ca.src[0] = Q;  ca.dst[0] = Qb;  ca.n[0] = nin;
    ca.src[1] = K;  ca.dst[1] = Kb;  ca.n[1] = nin;
    ca.src[2] = V;  ca.dst[2] = Vb;  ca.n[2] = nin;
    ca.src[3] = Wq; ca.dst[3] = Wqb; ca.n[3] = nw;
    ca.src[4] = Wk; ca.dst[4] = Wkb; ca.n[4] = nw;
    ca.src[5] = Wv; ca.dst[5] = Wvb; ca.n[5] = nw;
    ca.src[6] = Wo; ca.dst[6] = Wob; ca.n[6] = nw;
    ca.msrc = mask;
    ca.mdst = maskb;

    dim3 blk(256);
    cvt_all<<<dim3(nin / 1024, 8), blk, 0, stream>>>(ca);

    gemm_qkv<<<dim3(24, 32), blk, 0, stream>>>(Qb, Kb, Vb, Wqb, bq, bk, bv,
                                               Qf, Kf, Vt);

    attn_mfma<<<dim3(SEQ / 64, NH, BATCH), blk, 0, stream>>>(Qf, Kf, Vt, maskb, Xr);

    gemm_out<<<dim3(16, 32), blk, 0, stream>>>(Xr, Wob, bo, out);
}